// Round 1
// baseline (1656.014 us; speedup 1.0000x reference)
//
#include <hip/hip_runtime.h>
#include <hip/hip_bf16.h>

typedef __bf16 bf16x8_t __attribute__((ext_vector_type(8)));
typedef float f32x4_t __attribute__((ext_vector_type(4)));

#define B_ 2
#define T_ 2048
#define D_ 1024
#define DC_ 512
#define DM_ 1536
#define H_ 16
#define DE_ 4096
#define DG_ 1024
#define ROWS (B_*T_)   // 4096

__device__ __forceinline__ float sigmoid_f(float x) { return 1.f / (1.f + __expf(-x)); }

// ---------------------------------------------------------------------------
// Weight transpose + cast: W[K,N] fp32 -> Wt[N,K] bf16
// ---------------------------------------------------------------------------
__global__ __launch_bounds__(256)
void transpose_cast(const float* __restrict__ W, __hip_bfloat16* __restrict__ Wt,
                    int K, int N) {
    __shared__ float t[32][33];
    const int n0 = blockIdx.x * 32, k0 = blockIdx.y * 32;
    const int tx = threadIdx.x, ty = threadIdx.y;
#pragma unroll
    for (int r = 0; r < 4; ++r)
        t[ty + r * 8][tx] = W[(size_t)(k0 + ty + r * 8) * N + n0 + tx];
    __syncthreads();
#pragma unroll
    for (int r = 0; r < 4; ++r)
        Wt[(size_t)(n0 + ty + r * 8) * K + k0 + tx] = __float2bfloat16(t[tx][ty + r * 8]);
}

// ---------------------------------------------------------------------------
// LayerNorm over D=1024, fp32 in -> bf16 out. One block (256 thr) per row.
// ---------------------------------------------------------------------------
__global__ __launch_bounds__(256)
void ln_cast(const float* __restrict__ x, const float* __restrict__ w,
             const float* __restrict__ b, __hip_bfloat16* __restrict__ out) {
    const int row = blockIdx.x;
    const int tid = threadIdx.x;
    const float4 v = ((const float4*)(x + (size_t)row * D_))[tid];
    float s = v.x + v.y + v.z + v.w;
#pragma unroll
    for (int o = 32; o; o >>= 1) s += __shfl_down(s, o);
    __shared__ float red1[4], red2[4];
    if (!(tid & 63)) red1[tid >> 6] = s;
    __syncthreads();
    const float mu = (red1[0] + red1[1] + red1[2] + red1[3]) * (1.f / D_);
    const float dx = v.x - mu, dy = v.y - mu, dz = v.z - mu, dw = v.w - mu;
    float s2 = dx * dx + dy * dy + dz * dz + dw * dw;
#pragma unroll
    for (int o = 32; o; o >>= 1) s2 += __shfl_down(s2, o);
    if (!(tid & 63)) red2[tid >> 6] = s2;
    __syncthreads();
    const float var = (red2[0] + red2[1] + red2[2] + red2[3]) * (1.f / D_);
    const float rs = rsqrtf(var + 1e-5f);
    const float4 wv = ((const float4*)w)[tid];
    const float4 bv = ((const float4*)b)[tid];
    __hip_bfloat16* op = out + (size_t)row * D_ + tid * 4;
    op[0] = __float2bfloat16(dx * rs * wv.x + bv.x);
    op[1] = __float2bfloat16(dy * rs * wv.y + bv.y);
    op[2] = __float2bfloat16(dz * rs * wv.z + bv.z);
    op[3] = __float2bfloat16(dw * rs * wv.w + bv.w);
}

// ---------------------------------------------------------------------------
// bf16 MFMA GEMM: C[M,N] = A[M,K] @ Bt[N,K]^T + bias, epilogue variants.
// EPI 0: out bf16;  1: out fp32 = resid + v;  2: out bf16 = silu(v);
// EPI 3: out bf16 = sigmoid(v)
// 128x128 tile, BK=32, 256 threads (4 waves, 2x2 of 64x64), 4x4 MFMA/wave.
// ---------------------------------------------------------------------------
template <int EPI>
__global__ __launch_bounds__(256)
void gemm_bt(const __hip_bfloat16* __restrict__ A, const __hip_bfloat16* __restrict__ Bt,
             const float* __restrict__ bias, const float* __restrict__ resid,
             void* __restrict__ Cout, int M, int N, int K) {
    // LDS: [k-chunk of 8][row 0..127][8 bf16] -> frag reads are 16B sequential
    __shared__ __hip_bfloat16 As[4][128][8];
    __shared__ __hip_bfloat16 Bs[4][128][8];
    const int tid = threadIdx.x;
    const int m0 = blockIdx.y * 128;
    const int n0 = blockIdx.x * 128;
    const int lane = tid & 63;
    const int wave = tid >> 6;
    const int wm = (wave >> 1) * 64, wn = (wave & 1) * 64;
    const int kc = lane >> 4;        // k-chunk 0..3
    const int lr = lane & 15;

    f32x4_t acc[4][4] = {};

    for (int k0 = 0; k0 < K; k0 += 32) {
        // stage A and B tiles (each 128x32 bf16 = 8KB): 2 passes x 16B/thread
#pragma unroll
        for (int p = 0; p < 2; ++p) {
            const int idx = p * 256 + tid;        // 0..511
            const int row = idx >> 2, c = idx & 3;
            const uint4 va = *(const uint4*)(A + (size_t)(m0 + row) * K + k0 + c * 8);
            *(uint4*)(&As[c][row][0]) = va;
            const uint4 vb = *(const uint4*)(Bt + (size_t)(n0 + row) * K + k0 + c * 8);
            *(uint4*)(&Bs[c][row][0]) = vb;
        }
        __syncthreads();
        bf16x8_t af[4], bfr[4];
#pragma unroll
        for (int i = 0; i < 4; ++i) af[i] = *(const bf16x8_t*)(&As[kc][wm + i * 16 + lr][0]);
#pragma unroll
        for (int j = 0; j < 4; ++j) bfr[j] = *(const bf16x8_t*)(&Bs[kc][wn + j * 16 + lr][0]);
#pragma unroll
        for (int i = 0; i < 4; ++i)
#pragma unroll
            for (int j = 0; j < 4; ++j)
                acc[i][j] = __builtin_amdgcn_mfma_f32_16x16x32_bf16(af[i], bfr[j], acc[i][j], 0, 0, 0);
        __syncthreads();
    }

    // epilogue: D layout col=lane&15, row=(lane>>4)*4+reg
    const int rbase = kc * 4;
#pragma unroll
    for (int j = 0; j < 4; ++j) {
        const int col = n0 + wn + j * 16 + lr;
        const float bj = bias[col];
#pragma unroll
        for (int i = 0; i < 4; ++i) {
#pragma unroll
            for (int r = 0; r < 4; ++r) {
                const int row = m0 + wm + i * 16 + rbase + r;
                const size_t o = (size_t)row * N + col;
                const float v = acc[i][j][r] + bj;
                if (EPI == 0)      ((__hip_bfloat16*)Cout)[o] = __float2bfloat16(v);
                else if (EPI == 1) ((float*)Cout)[o] = resid[o] + v;
                else if (EPI == 2) ((__hip_bfloat16*)Cout)[o] = __float2bfloat16(v * sigmoid_f(v));
                else               ((__hip_bfloat16*)Cout)[o] = __float2bfloat16(sigmoid_f(v));
            }
        }
    }
}

// ---------------------------------------------------------------------------
// Flash attention (vector ALU, online softmax). Grid: (32 q-tiles, 32 b*h).
// Q[rows,512] bf16 (head h at cols h*32..+32), V/Y [rows,1536] (h*96..+96).
// Block 256: thread t -> row r=t>>2, quarter q=t&3 -> 24 output cols.
// ---------------------------------------------------------------------------
__global__ __launch_bounds__(256)
void attn_fwd(const __hip_bfloat16* __restrict__ Q, const __hip_bfloat16* __restrict__ Kb,
              const __hip_bfloat16* __restrict__ Vb, __hip_bfloat16* __restrict__ Y) {
    __shared__ float Qs[64][33];
    __shared__ float Ks[64][36];
    __shared__ float Vs[64][100];
    __shared__ float Ss[64][65];
    const int tid = threadIdx.x;
    const int q0 = blockIdx.x * 64;
    const int bh = blockIdx.y;
    const int b = bh >> 4, h = bh & 15;
    const size_t qkbase = (size_t)b * T_ * DC_ + h * 32;
    const size_t vbase  = (size_t)b * T_ * DM_ + h * 96;

#pragma unroll
    for (int p = 0; p < 8; ++p) {     // 64x32 Q tile
        const int idx = p * 256 + tid;
        const int r = idx >> 5, d = idx & 31;
        Qs[r][d] = __bfloat162float(Q[qkbase + (size_t)(q0 + r) * DC_ + d]);
    }
    __syncthreads();

    const int r  = tid >> 2;
    const int qq = tid & 3;
    const int c0 = qq * 24;
    float qreg[32];
#pragma unroll
    for (int d = 0; d < 32; ++d) qreg[d] = Qs[r][d];

    float accv[24];
#pragma unroll
    for (int i = 0; i < 24; ++i) accv[i] = 0.f;
    float mrow = -1e30f, lrow = 0.f;
    const float scale = 0.17677669529663687f;   // 1/sqrt(32)
    const int ntiles = q0 / 64 + 1;

    for (int t = 0; t < ntiles; ++t) {
        const int k0 = t * 64;
#pragma unroll
        for (int p = 0; p < 8; ++p) {   // 64x32 K tile
            const int idx = p * 256 + tid;
            const int rr = idx >> 5, d = idx & 31;
            Ks[rr][d] = __bfloat162float(Kb[qkbase + (size_t)(k0 + rr) * DC_ + d]);
        }
#pragma unroll
        for (int p = 0; p < 24; ++p) {  // 64x96 V tile
            const int idx = p * 256 + tid;
            const int rr = idx / 96, d = idx % 96;
            Vs[rr][d] = __bfloat162float(Vb[vbase + (size_t)(k0 + rr) * DM_ + d]);
        }
        __syncthreads();

        // scores: each thread 16 cols (kk = qq + 4*s) of its row
#pragma unroll
        for (int s = 0; s < 16; ++s) {
            const int kk = qq + s * 4;
            const float4* krow = (const float4*)(&Ks[kk][0]);
            float dot = 0.f;
#pragma unroll
            for (int i = 0; i < 8; ++i) {
                const float4 kv = krow[i];
                dot += qreg[i * 4] * kv.x + qreg[i * 4 + 1] * kv.y +
                       qreg[i * 4 + 2] * kv.z + qreg[i * 4 + 3] * kv.w;
            }
            dot *= scale;
            if (k0 + kk > q0 + r) dot = -1e30f;   // causal mask
            Ss[r][kk] = dot;
        }
        __syncthreads();

        // online softmax update for this tile
        float mt = -1e30f;
        for (int kk = 0; kk < 64; ++kk) mt = fmaxf(mt, Ss[r][kk]);
        const float newm = fmaxf(mrow, mt);
        const float alpha = __expf(mrow - newm);
        lrow *= alpha;
#pragma unroll
        for (int i = 0; i < 24; ++i) accv[i] *= alpha;
        for (int kk = 0; kk < 64; ++kk) {
            const float p = __expf(Ss[r][kk] - newm);
            lrow += p;
            const float4* vrow = (const float4*)(&Vs[kk][c0]);
#pragma unroll
            for (int i = 0; i < 6; ++i) {
                const float4 vv = vrow[i];
                accv[i * 4 + 0] += p * vv.x;
                accv[i * 4 + 1] += p * vv.y;
                accv[i * 4 + 2] += p * vv.z;
                accv[i * 4 + 3] += p * vv.w;
            }
        }
        mrow = newm;
        __syncthreads();
    }

    const float inv = 1.f / lrow;
    __hip_bfloat16* yp = Y + vbase + (size_t)(q0 + r) * DM_ + c0;
#pragma unroll
    for (int i = 0; i < 24; ++i) yp[i] = __float2bfloat16(accv[i] * inv);
}

// ---------------------------------------------------------------------------
// su = silu(e*g), bf16 in/out, vectorized x8
// ---------------------------------------------------------------------------
__global__ __launch_bounds__(256)
void silu_mul(const __hip_bfloat16* __restrict__ e, const __hip_bfloat16* __restrict__ g,
              __hip_bfloat16* __restrict__ o) {
    const size_t i = ((size_t)blockIdx.x * 256 + threadIdx.x) * 8;
    union U8 { uint4 v; __hip_bfloat16 h[8]; };
    U8 ue, ug, uo;
    ue.v = *(const uint4*)(e + i);
    ug.v = *(const uint4*)(g + i);
#pragma unroll
    for (int j = 0; j < 8; ++j) {
        const float z = __bfloat162float(ue.h[j]) * __bfloat162float(ug.h[j]);
        uo.h[j] = __float2bfloat16(z * sigmoid_f(z));
    }
    *(uint4*)(o + i) = uo.v;
}

// ---------------------------------------------------------------------------
extern "C" void kernel_launch(void* const* d_in, const int* in_sizes, int n_in,
                              void* d_out, int out_size, void* d_ws, size_t ws_size,
                              hipStream_t stream) {
    const float* x     = (const float*)d_in[0];
    const float* ln1_w = (const float*)d_in[2];
    const float* ln1_b = (const float*)d_in[3];
    const float* wq = (const float*)d_in[4];  const float* bq = (const float*)d_in[5];
    const float* wk = (const float*)d_in[6];  const float* bk = (const float*)d_in[7];
    const float* wv = (const float*)d_in[8];  const float* bv = (const float*)d_in[9];
    const float* wo = (const float*)d_in[10]; const float* bo = (const float*)d_in[11];
    const float* ln2_w = (const float*)d_in[12];
    const float* ln2_b = (const float*)d_in[13];
    const float* we = (const float*)d_in[14]; const float* be = (const float*)d_in[15];
    const float* wg = (const float*)d_in[16]; const float* bg = (const float*)d_in[17];
    const float* wu = (const float*)d_in[18]; const float* bu = (const float*)d_in[19];
    const float* wc = (const float*)d_in[20]; const float* bc = (const float*)d_in[21];
    float* out = (float*)d_out;

    char* ws = (char*)d_ws;
    size_t off = 0;
    auto alloc = [&](size_t bytes) {
        size_t o = off;
        off += (bytes + 255) & ~(size_t)255;
        return o;
    };
    typedef __hip_bfloat16 bf16;
    bf16* wqT  = (bf16*)(ws + alloc((size_t)DC_ * D_ * 2));
    bf16* wkT  = (bf16*)(ws + alloc((size_t)DC_ * D_ * 2));
    bf16* wvT  = (bf16*)(ws + alloc((size_t)DM_ * D_ * 2));
    bf16* woT  = (bf16*)(ws + alloc((size_t)D_ * DM_ * 2));
    bf16* weT  = (bf16*)(ws + alloc((size_t)DE_ * D_ * 2));
    bf16* wgT  = (bf16*)(ws + alloc((size_t)DG_ * D_ * 2));
    bf16* wuT  = (bf16*)(ws + alloc((size_t)DE_ * DG_ * 2));
    bf16* wcT  = (bf16*)(ws + alloc((size_t)D_ * DE_ * 2));
    size_t pool0 = alloc((size_t)ROWS * D_ * 2);    // x1b; later reused for sub
    bf16* x1b  = (bf16*)(ws + pool0);
    bf16* qb   = (bf16*)(ws + alloc((size_t)ROWS * DC_ * 2));
    bf16* kb   = (bf16*)(ws + alloc((size_t)ROWS * DC_ * 2));
    bf16* vb   = (bf16*)(ws + alloc((size_t)ROWS * DM_ * 2));
    bf16* yb   = (bf16*)(ws + alloc((size_t)ROWS * DM_ * 2));
    float* xmid = (float*)(ws + alloc((size_t)ROWS * D_ * 4));
    bf16* x2b  = (bf16*)(ws + alloc((size_t)ROWS * D_ * 2));
    bf16* eb   = (bf16*)(ws + alloc((size_t)ROWS * DE_ * 2));
    bf16* hb   = (bf16*)(ws + alloc((size_t)ROWS * DG_ * 2));
    bf16* gb   = (bf16*)(ws + alloc((size_t)ROWS * DE_ * 2));
    bf16* sub  = (bf16*)(ws + pool0);   // reuse x1b..yb region (40MB >= 32MB), dead by then

    const dim3 tb(32, 8);
    transpose_cast<<<dim3(DC_ / 32, D_ / 32), tb, 0, stream>>>(wq, wqT, D_, DC_);
    transpose_cast<<<dim3(DC_ / 32, D_ / 32), tb, 0, stream>>>(wk, wkT, D_, DC_);
    transpose_cast<<<dim3(DM_ / 32, D_ / 32), tb, 0, stream>>>(wv, wvT, D_, DM_);
    transpose_cast<<<dim3(D_ / 32, DM_ / 32), tb, 0, stream>>>(wo, woT, DM_, D_);
    transpose_cast<<<dim3(DE_ / 32, D_ / 32), tb, 0, stream>>>(we, weT, D_, DE_);
    transpose_cast<<<dim3(DG_ / 32, D_ / 32), tb, 0, stream>>>(wg, wgT, D_, DG_);
    transpose_cast<<<dim3(DE_ / 32, DG_ / 32), tb, 0, stream>>>(wu, wuT, DG_, DE_);
    transpose_cast<<<dim3(D_ / 32, DE_ / 32), tb, 0, stream>>>(wc, wcT, DE_, D_);

    ln_cast<<<ROWS, 256, 0, stream>>>(x, ln1_w, ln1_b, x1b);

    gemm_bt<0><<<dim3(DC_ / 128, ROWS / 128), 256, 0, stream>>>(x1b, wqT, bq, nullptr, qb, ROWS, DC_, D_);
    gemm_bt<0><<<dim3(DC_ / 128, ROWS / 128), 256, 0, stream>>>(x1b, wkT, bk, nullptr, kb, ROWS, DC_, D_);
    gemm_bt<0><<<dim3(DM_ / 128, ROWS / 128), 256, 0, stream>>>(x1b, wvT, bv, nullptr, vb, ROWS, DM_, D_);

    attn_fwd<<<dim3(T_ / 64, B_ * H_), 256, 0, stream>>>(qb, kb, vb, yb);

    gemm_bt<1><<<dim3(D_ / 128, ROWS / 128), 256, 0, stream>>>(yb, woT, bo, x, xmid, ROWS, D_, DM_);

    ln_cast<<<ROWS, 256, 0, stream>>>(xmid, ln2_w, ln2_b, x2b);

    gemm_bt<0><<<dim3(DE_ / 128, ROWS / 128), 256, 0, stream>>>(x2b, weT, be, nullptr, eb, ROWS, DE_, D_);
    gemm_bt<2><<<dim3(DG_ / 128, ROWS / 128), 256, 0, stream>>>(x2b, wgT, bg, nullptr, hb, ROWS, DG_, D_);
    gemm_bt<3><<<dim3(DE_ / 128, ROWS / 128), 256, 0, stream>>>(hb, wuT, bu, nullptr, gb, ROWS, DE_, DG_);

    silu_mul<<<(ROWS * (size_t)DE_) / (256 * 8), 256, 0, stream>>>(eb, gb, sub);

    gemm_bt<1><<<dim3(D_ / 128, ROWS / 128), 256, 0, stream>>>(sub, wcT, bc, xmid, out, ROWS, D_, DE_);
}

// Round 3
// 723.101 us; speedup vs baseline: 2.2902x; 2.2902x over previous
//
#include <hip/hip_runtime.h>
#include <hip/hip_bf16.h>

typedef __bf16 bf16x8_t __attribute__((ext_vector_type(8)));
typedef float f32x4_t __attribute__((ext_vector_type(4)));

#define B_ 2
#define T_ 2048
#define D_ 1024
#define DC_ 512
#define DM_ 1536
#define H_ 16
#define DE_ 4096
#define DG_ 1024
#define ROWS (B_*T_)   // 4096
#define MB (1u<<20)

__device__ __forceinline__ float sigmoid_f(float x) { return 1.f / (1.f + __expf(-x)); }

// ---------------------------------------------------------------------------
// Weight transpose + cast: W[K,N] fp32 -> Wt[N,K] bf16
// ---------------------------------------------------------------------------
__global__ __launch_bounds__(256)
void transpose_cast(const float* __restrict__ W, __hip_bfloat16* __restrict__ Wt,
                    int K, int N) {
    __shared__ float t[32][33];
    const int n0 = blockIdx.x * 32, k0 = blockIdx.y * 32;
    const int tx = threadIdx.x, ty = threadIdx.y;
#pragma unroll
    for (int r = 0; r < 4; ++r)
        t[ty + r * 8][tx] = W[(size_t)(k0 + ty + r * 8) * N + n0 + tx];
    __syncthreads();
#pragma unroll
    for (int r = 0; r < 4; ++r)
        Wt[(size_t)(n0 + ty + r * 8) * K + k0 + tx] = __float2bfloat16(t[tx][ty + r * 8]);
}

// ---------------------------------------------------------------------------
// V transpose: Vb[b*T+t][h*96+d] bf16 -> Vt[(bh*96+d)][t] bf16
// ---------------------------------------------------------------------------
__global__ __launch_bounds__(256)
void transpose_v(const __hip_bfloat16* __restrict__ Vb, __hip_bfloat16* __restrict__ Vt) {
    __shared__ __hip_bfloat16 t[32][33];
    const int bh = blockIdx.z;
    const int b = bh >> 4, h = bh & 15;
    const int t0 = blockIdx.x * 32;   // T dim
    const int d0 = blockIdx.y * 32;   // head dim (0..95)
    const int tx = threadIdx.x, ty = threadIdx.y;  // (32,8)
#pragma unroll
    for (int r = 0; r < 4; ++r)
        t[ty + r * 8][tx] = Vb[(size_t)(b * T_ + t0 + ty + r * 8) * DM_ + h * 96 + d0 + tx];
    __syncthreads();
#pragma unroll
    for (int r = 0; r < 4; ++r)
        Vt[((size_t)bh * 96 + d0 + ty + r * 8) * T_ + t0 + tx] = t[tx][ty + r * 8];
}

// ---------------------------------------------------------------------------
// LayerNorm over D=1024, fp32 in -> bf16 out. One block (256 thr) per row.
// ---------------------------------------------------------------------------
__global__ __launch_bounds__(256)
void ln_cast(const float* __restrict__ x, const float* __restrict__ w,
             const float* __restrict__ b, __hip_bfloat16* __restrict__ out) {
    const int row = blockIdx.x;
    const int tid = threadIdx.x;
    const float4 v = ((const float4*)(x + (size_t)row * D_))[tid];
    float s = v.x + v.y + v.z + v.w;
#pragma unroll
    for (int o = 32; o; o >>= 1) s += __shfl_down(s, o);
    __shared__ float red1[4], red2[4];
    if (!(tid & 63)) red1[tid >> 6] = s;
    __syncthreads();
    const float mu = (red1[0] + red1[1] + red1[2] + red1[3]) * (1.f / D_);
    const float dx = v.x - mu, dy = v.y - mu, dz = v.z - mu, dw = v.w - mu;
    float s2 = dx * dx + dy * dy + dz * dz + dw * dw;
#pragma unroll
    for (int o = 32; o; o >>= 1) s2 += __shfl_down(s2, o);
    if (!(tid & 63)) red2[tid >> 6] = s2;
    __syncthreads();
    const float var = (red2[0] + red2[1] + red2[2] + red2[3]) * (1.f / D_);
    const float rs = rsqrtf(var + 1e-5f);
    const float4 wv = ((const float4*)w)[tid];
    const float4 bv = ((const float4*)b)[tid];
    __hip_bfloat16* op = out + (size_t)row * D_ + tid * 4;
    op[0] = __float2bfloat16(dx * rs * wv.x + bv.x);
    op[1] = __float2bfloat16(dy * rs * wv.y + bv.y);
    op[2] = __float2bfloat16(dz * rs * wv.z + bv.z);
    op[3] = __float2bfloat16(dw * rs * wv.w + bv.w);
}

// ---------------------------------------------------------------------------
// bf16 MFMA GEMM: C[M,N] = A[M,K] @ Bt[N,K]^T + bias, epilogue variants.
// EPI 0: out bf16;  1: out fp32 = resid + v;  2: out bf16 = silu(v);
// EPI 4: out bf16 = silu(Ein * sigmoid(v))  (Ein read at same index; may
//        alias Cout — each element is read-then-written by one thread)
// ---------------------------------------------------------------------------
template <int EPI>
__global__ __launch_bounds__(256)
void gemm_bt(const __hip_bfloat16* __restrict__ A, const __hip_bfloat16* __restrict__ Bt,
             const float* __restrict__ bias, const float* __restrict__ resid,
             const __hip_bfloat16* __restrict__ Ein,
             void* __restrict__ Cout, int M, int N, int K) {
    __shared__ __hip_bfloat16 As[4][128][8];
    __shared__ __hip_bfloat16 Bs[4][128][8];
    const int tid = threadIdx.x;
    const int m0 = blockIdx.y * 128;
    const int n0 = blockIdx.x * 128;
    const int lane = tid & 63;
    const int wave = tid >> 6;
    const int wm = (wave >> 1) * 64, wn = (wave & 1) * 64;
    const int kc = lane >> 4;
    const int lr = lane & 15;

    f32x4_t acc[4][4] = {};

    for (int k0 = 0; k0 < K; k0 += 32) {
#pragma unroll
        for (int p = 0; p < 2; ++p) {
            const int idx = p * 256 + tid;
            const int row = idx >> 2, c = idx & 3;
            const uint4 va = *(const uint4*)(A + (size_t)(m0 + row) * K + k0 + c * 8);
            *(uint4*)(&As[c][row][0]) = va;
            const uint4 vb = *(const uint4*)(Bt + (size_t)(n0 + row) * K + k0 + c * 8);
            *(uint4*)(&Bs[c][row][0]) = vb;
        }
        __syncthreads();
        bf16x8_t af[4], bfr[4];
#pragma unroll
        for (int i = 0; i < 4; ++i) af[i] = *(const bf16x8_t*)(&As[kc][wm + i * 16 + lr][0]);
#pragma unroll
        for (int j = 0; j < 4; ++j) bfr[j] = *(const bf16x8_t*)(&Bs[kc][wn + j * 16 + lr][0]);
#pragma unroll
        for (int i = 0; i < 4; ++i)
#pragma unroll
            for (int j = 0; j < 4; ++j)
                acc[i][j] = __builtin_amdgcn_mfma_f32_16x16x32_bf16(af[i], bfr[j], acc[i][j], 0, 0, 0);
        __syncthreads();
    }

    const int rbase = kc * 4;
#pragma unroll
    for (int j = 0; j < 4; ++j) {
        const int col = n0 + wn + j * 16 + lr;
        const float bj = bias[col];
#pragma unroll
        for (int i = 0; i < 4; ++i) {
#pragma unroll
            for (int r = 0; r < 4; ++r) {
                const int row = m0 + wm + i * 16 + rbase + r;
                const size_t o = (size_t)row * N + col;
                const float v = acc[i][j][r] + bj;
                if (EPI == 0)      ((__hip_bfloat16*)Cout)[o] = __float2bfloat16(v);
                else if (EPI == 1) ((float*)Cout)[o] = resid[o] + v;
                else if (EPI == 2) ((__hip_bfloat16*)Cout)[o] = __float2bfloat16(v * sigmoid_f(v));
                else {  // EPI 4
                    const float z = __bfloat162float(Ein[o]) * sigmoid_f(v);
                    ((__hip_bfloat16*)Cout)[o] = __float2bfloat16(z * sigmoid_f(z));
                }
            }
        }
    }
}

// ---------------------------------------------------------------------------
// MFMA flash attention. Grid (T/64, B*H), 256 thr (4 waves x 16 q-rows).
// ---------------------------------------------------------------------------
__global__ __launch_bounds__(256)
void attn_mfma(const __hip_bfloat16* __restrict__ Q, const __hip_bfloat16* __restrict__ Kb,
               const __hip_bfloat16* __restrict__ Vt, __hip_bfloat16* __restrict__ Y) {
    __shared__ __hip_bfloat16 Ks[64][40];      // 64x32 data, pad->80B rows
    __shared__ __hip_bfloat16 Vts[96][72];     // 96x64 data, pad->144B rows
    __shared__ __hip_bfloat16 Ps[4][16][72];   // per-wave 16x64 P tile
    const int tid = threadIdx.x;
    const int lane = tid & 63;
    const int w = tid >> 6;
    const int c = lane & 15;
    const int quad = lane >> 4;
    const int q0 = blockIdx.x * 64;
    const int bh = blockIdx.y;
    const int b = bh >> 4, h = bh & 15;
    const size_t qkbase = (size_t)b * T_ * DC_ + h * 32;
    const size_t vtbase = (size_t)bh * 96 * T_;
    const size_t ybase = (size_t)b * T_ * DM_ + h * 96;

    const int qrow_a = q0 + w * 16 + c;
    const bf16x8_t qf = *(const bf16x8_t*)(Q + qkbase + (size_t)qrow_a * DC_ + quad * 8);

    f32x4_t o[6] = {};
    float mrow[4], lrow[4];
#pragma unroll
    for (int r = 0; r < 4; ++r) { mrow[r] = -1e30f; lrow[r] = 0.f; }
    const int row_c = q0 + w * 16 + quad * 4;
    const float scale = 0.17677669529663687f;   // 1/sqrt(32)
    const int ntiles = blockIdx.x + 1;

    for (int t = 0; t < ntiles; ++t) {
        const int k0 = t * 64;
        {
            const int kr = tid >> 2, kc4 = tid & 3;
            *(uint4*)(&Ks[kr][kc4 * 8]) =
                *(const uint4*)(Kb + qkbase + (size_t)(k0 + kr) * DC_ + kc4 * 8);
#pragma unroll
            for (int p = 0; p < 3; ++p) {
                const int idx = p * 256 + tid;
                const int vr = idx >> 3, vc = idx & 7;
                *(uint4*)(&Vts[vr][vc * 8]) =
                    *(const uint4*)(Vt + vtbase + (size_t)vr * T_ + k0 + vc * 8);
            }
        }
        __syncthreads();

        f32x4_t s[4];
#pragma unroll
        for (int t2 = 0; t2 < 4; ++t2) {
            const bf16x8_t kf = *(const bf16x8_t*)(&Ks[t2 * 16 + c][quad * 8]);
            f32x4_t z = {0.f, 0.f, 0.f, 0.f};
            s[t2] = __builtin_amdgcn_mfma_f32_16x16x32_bf16(qf, kf, z, 0, 0, 0);
        }

        float p[4][4];
#pragma unroll
        for (int t2 = 0; t2 < 4; ++t2) {
            const int col = k0 + t2 * 16 + c;
#pragma unroll
            for (int r = 0; r < 4; ++r) {
                float v = s[t2][r] * scale;
                if (col > row_c + r) v = -1e30f;
                p[t2][r] = v;
            }
        }

#pragma unroll
        for (int r = 0; r < 4; ++r) {
            float mx = fmaxf(fmaxf(p[0][r], p[1][r]), fmaxf(p[2][r], p[3][r]));
#pragma unroll
            for (int o2 = 1; o2 < 16; o2 <<= 1) mx = fmaxf(mx, __shfl_xor(mx, o2));
            const float mnew = fmaxf(mrow[r], mx);
            const float alpha = __expf(mrow[r] - mnew);
            mrow[r] = mnew;
            float rsum = 0.f;
#pragma unroll
            for (int t2 = 0; t2 < 4; ++t2) {
                p[t2][r] = __expf(p[t2][r] - mnew);
                rsum += p[t2][r];
            }
#pragma unroll
            for (int o2 = 1; o2 < 16; o2 <<= 1) rsum += __shfl_xor(rsum, o2);
            lrow[r] = lrow[r] * alpha + rsum;
#pragma unroll
            for (int nb = 0; nb < 6; ++nb) o[nb][r] *= alpha;
        }

#pragma unroll
        for (int t2 = 0; t2 < 4; ++t2)
#pragma unroll
            for (int r = 0; r < 4; ++r)
                Ps[w][quad * 4 + r][t2 * 16 + c] = __float2bfloat16(p[t2][r]);

        const bf16x8_t pf0 = *(const bf16x8_t*)(&Ps[w][c][quad * 8]);
        const bf16x8_t pf1 = *(const bf16x8_t*)(&Ps[w][c][32 + quad * 8]);

#pragma unroll
        for (int nb = 0; nb < 6; ++nb) {
            const bf16x8_t vf0 = *(const bf16x8_t*)(&Vts[nb * 16 + c][quad * 8]);
            o[nb] = __builtin_amdgcn_mfma_f32_16x16x32_bf16(pf0, vf0, o[nb], 0, 0, 0);
            const bf16x8_t vf1 = *(const bf16x8_t*)(&Vts[nb * 16 + c][32 + quad * 8]);
            o[nb] = __builtin_amdgcn_mfma_f32_16x16x32_bf16(pf1, vf1, o[nb], 0, 0, 0);
        }
        __syncthreads();
    }

#pragma unroll
    for (int r = 0; r < 4; ++r) {
        const float inv = 1.f / lrow[r];
        const size_t rowoff = ybase + (size_t)(row_c + r) * DM_;
#pragma unroll
        for (int nb = 0; nb < 6; ++nb)
            Y[rowoff + nb * 16 + c] = __float2bfloat16(o[nb][r] * inv);
    }
}

// ---------------------------------------------------------------------------
// Workspace map (122 MB total; phase-aliased, lifetimes stream-ordered):
//   [  0, 34) weights bf16 (persistent)
//   [ 34, 42) x1b  -> x2b
//   [ 42, 46) qb
//   [ 46, 50) kb
//   [ 50, 62) vb   -> yb -> hb(8MB)
//   [ 62, 74) vt
//   [ 74, 90) xmid fp32 (persistent from wo-GEMM to final)
//   [ 90,122) eb   -> silu-gated product (in-place via EPI 4)
// ---------------------------------------------------------------------------
extern "C" void kernel_launch(void* const* d_in, const int* in_sizes, int n_in,
                              void* d_out, int out_size, void* d_ws, size_t ws_size,
                              hipStream_t stream) {
    const float* x     = (const float*)d_in[0];
    const float* ln1_w = (const float*)d_in[2];
    const float* ln1_b = (const float*)d_in[3];
    const float* wq = (const float*)d_in[4];  const float* bq = (const float*)d_in[5];
    const float* wk = (const float*)d_in[6];  const float* bk = (const float*)d_in[7];
    const float* wv = (const float*)d_in[8];  const float* bv = (const float*)d_in[9];
    const float* wo = (const float*)d_in[10]; const float* bo = (const float*)d_in[11];
    const float* ln2_w = (const float*)d_in[12];
    const float* ln2_b = (const float*)d_in[13];
    const float* we = (const float*)d_in[14]; const float* be = (const float*)d_in[15];
    const float* wg = (const float*)d_in[16]; const float* bg = (const float*)d_in[17];
    const float* wu = (const float*)d_in[18]; const float* bu = (const float*)d_in[19];
    const float* wc = (const float*)d_in[20]; const float* bc = (const float*)d_in[21];
    float* out = (float*)d_out;

    char* ws = (char*)d_ws;
    typedef __hip_bfloat16 bf16;
    bf16* wqT  = (bf16*)(ws + (size_t) 0 * MB);
    bf16* wkT  = (bf16*)(ws + (size_t) 1 * MB);
    bf16* wvT  = (bf16*)(ws + (size_t) 2 * MB);
    bf16* woT  = (bf16*)(ws + (size_t) 5 * MB);
    bf16* weT  = (bf16*)(ws + (size_t) 8 * MB);
    bf16* wgT  = (bf16*)(ws + (size_t)16 * MB);
    bf16* wuT  = (bf16*)(ws + (size_t)18 * MB);
    bf16* wcT  = (bf16*)(ws + (size_t)26 * MB);
    bf16* x1b  = (bf16*)(ws + (size_t)34 * MB);   // later x2b
    bf16* x2b  = x1b;
    bf16* qb   = (bf16*)(ws + (size_t)42 * MB);
    bf16* kb   = (bf16*)(ws + (size_t)46 * MB);
    bf16* vb   = (bf16*)(ws + (size_t)50 * MB);   // later yb, then hb
    bf16* yb   = vb;
    bf16* hb   = vb;
    bf16* vt   = (bf16*)(ws + (size_t)62 * MB);
    float* xmid = (float*)(ws + (size_t)74 * MB);
    bf16* eb   = (bf16*)(ws + (size_t)90 * MB);   // EPI-4 rewrites in place

    const dim3 tb(32, 8);
    transpose_cast<<<dim3(DC_ / 32, D_ / 32), tb, 0, stream>>>(wq, wqT, D_, DC_);
    transpose_cast<<<dim3(DC_ / 32, D_ / 32), tb, 0, stream>>>(wk, wkT, D_, DC_);
    transpose_cast<<<dim3(DM_ / 32, D_ / 32), tb, 0, stream>>>(wv, wvT, D_, DM_);
    transpose_cast<<<dim3(D_ / 32, DM_ / 32), tb, 0, stream>>>(wo, woT, DM_, D_);
    transpose_cast<<<dim3(DE_ / 32, D_ / 32), tb, 0, stream>>>(we, weT, D_, DE_);
    transpose_cast<<<dim3(DG_ / 32, D_ / 32), tb, 0, stream>>>(wg, wgT, D_, DG_);
    transpose_cast<<<dim3(DE_ / 32, DG_ / 32), tb, 0, stream>>>(wu, wuT, DG_, DE_);
    transpose_cast<<<dim3(D_ / 32, DE_ / 32), tb, 0, stream>>>(wc, wcT, DE_, D_);

    ln_cast<<<ROWS, 256, 0, stream>>>(x, ln1_w, ln1_b, x1b);

    gemm_bt<0><<<dim3(DC_ / 128, ROWS / 128), 256, 0, stream>>>(x1b, wqT, bq, nullptr, nullptr, qb, ROWS, DC_, D_);
    gemm_bt<0><<<dim3(DC_ / 128, ROWS / 128), 256, 0, stream>>>(x1b, wkT, bk, nullptr, nullptr, kb, ROWS, DC_, D_);
    gemm_bt<0><<<dim3(DM_ / 128, ROWS / 128), 256, 0, stream>>>(x1b, wvT, bv, nullptr, nullptr, vb, ROWS, DM_, D_);

    transpose_v<<<dim3(T_ / 32, 3, B_ * H_), tb, 0, stream>>>(vb, vt);

    attn_mfma<<<dim3(T_ / 64, B_ * H_), 256, 0, stream>>>(qb, kb, vt, yb);

    gemm_bt<1><<<dim3(D_ / 128, ROWS / 128), 256, 0, stream>>>(yb, woT, bo, x, nullptr, xmid, ROWS, D_, DM_);

    ln_cast<<<ROWS, 256, 0, stream>>>(xmid, ln2_w, ln2_b, x2b);

    gemm_bt<0><<<dim3(DE_ / 128, ROWS / 128), 256, 0, stream>>>(x2b, weT, be, nullptr, nullptr, eb, ROWS, DE_, D_);
    gemm_bt<2><<<dim3(DG_ / 128, ROWS / 128), 256, 0, stream>>>(x2b, wgT, bg, nullptr, nullptr, hb, ROWS, DG_, D_);
    // wu GEMM with fused gate+silu, writing the gated product in place over eb
    gemm_bt<4><<<dim3(DE_ / 128, ROWS / 128), 256, 0, stream>>>(hb, wuT, bu, nullptr, eb, eb, ROWS, DE_, DG_);

    gemm_bt<1><<<dim3(D_ / 128, ROWS / 128), 256, 0, stream>>>(eb, wcT, bc, xmid, nullptr, out, ROWS, D_, DE_);
}